// Round 1
// baseline (234.046 us; speedup 1.0000x reference)
//
#include <hip/hip_runtime.h>

// Shapes (fixed): B=64, C_IN=512, T=16, C_OUT=512, K=3, E=16
// ws layout (floats):
//   rf     @ 0        : 64*16          = 1024
//   pooled @ 1024     : [c][b] 512*64  = 32768
//   xt     @ 33792    : [i][b][20]     = 512*64*20 = 655360  (t'=t+1, zero pads)
//   part   @ 689152   : [ic][b][o][t]  = 8*64*512*16 = 4194304
// total = 4,883,456 floats = 19.5 MB

// K1: transpose x -> xt[i][b][20] (zero-padded for conv), and pooled[c][b] = mean_t x[b][c][t]
__global__ __launch_bounds__(256) void k1_transpose_pool(const float* __restrict__ x,
                                                         float* __restrict__ pooled,
                                                         float* __restrict__ xt) {
  int g = blockIdx.x * 256 + threadIdx.x;  // 0..32767 : c = g>>6, b = g&63
  int c = g >> 6;
  int b = g & 63;
  const float4* xb = (const float4*)(x + ((size_t)b * 512 + c) * 16);
  float4 v0 = xb[0], v1 = xb[1], v2 = xb[2], v3 = xb[3];
  float s = v0.x + v0.y + v0.z + v0.w + v1.x + v1.y + v1.z + v1.w +
            v2.x + v2.y + v2.z + v2.w + v3.x + v3.y + v3.z + v3.w;
  pooled[c * 64 + b] = s * 0.0625f;  // mean over T=16
  float4* row = (float4*)(xt + ((size_t)c * 64 + b) * 20);
  row[0] = make_float4(0.f, v0.x, v0.y, v0.z);
  row[1] = make_float4(v0.w, v1.x, v1.y, v1.z);
  row[2] = make_float4(v1.w, v2.x, v2.y, v2.z);
  row[3] = make_float4(v2.w, v3.x, v3.y, v3.z);
  row[4] = make_float4(v3.w, 0.f, 0.f, 0.f);
}

// K1b: rf[b][e] = sum_c pooled[b][c]*rf_w[e][c] + rf_b[e]
__global__ __launch_bounds__(256) void k1b_rf(const float* __restrict__ pooled,
                                              const float* __restrict__ rf_w,
                                              const float* __restrict__ rf_b,
                                              float* __restrict__ rf) {
  __shared__ __align__(16) float ps[16 * 520];   // [b_local][c]
  __shared__ __align__(16) float wsm[16 * 520];  // [e][c]
  int tid = threadIdx.x, bg = blockIdx.x;
  // stage rf_w (16x512)
#pragma unroll
  for (int j = 0; j < 8; ++j) {
    int g = tid + j * 256;  // 0..2047
    int e = g >> 7, q = g & 127;
    *(float4*)&wsm[e * 520 + q * 4] = *(const float4*)&rf_w[e * 512 + q * 4];
  }
  // stage pooled columns bg*16..bg*16+15, transposed to [b_local][c]
#pragma unroll
  for (int j = 0; j < 8; ++j) {
    int g = tid + j * 256;  // 0..2047
    int c = g >> 2, q = g & 3;
    float4 v = *(const float4*)&pooled[c * 64 + bg * 16 + q * 4];
    ps[(q * 4 + 0) * 520 + c] = v.x;
    ps[(q * 4 + 1) * 520 + c] = v.y;
    ps[(q * 4 + 2) * 520 + c] = v.z;
    ps[(q * 4 + 3) * 520 + c] = v.w;
  }
  __syncthreads();
  int bl = tid >> 4, e = tid & 15;
  const float4* pr = (const float4*)&ps[bl * 520];
  const float4* wr = (const float4*)&wsm[e * 520];
  float s0 = 0, s1 = 0, s2 = 0, s3 = 0;
#pragma unroll 8
  for (int c4 = 0; c4 < 128; ++c4) {
    float4 p = pr[c4];
    float4 w = wr[c4];
    s0 = fmaf(p.x, w.x, s0);
    s1 = fmaf(p.y, w.y, s1);
    s2 = fmaf(p.z, w.z, s2);
    s3 = fmaf(p.w, w.w, s3);
  }
  rf[(bg * 16 + bl) * 16 + e] = s0 + s1 + s2 + s3 + rf_b[e];
}

// K2: fused synthesis + conv. Block = (o_tile of 8, i_chunk of 64). lane=b, wave=o-pair.
__global__ __launch_bounds__(256) void k2_main(const float* __restrict__ weight,
                                               const float* __restrict__ xt,
                                               const float* __restrict__ rf,
                                               float* __restrict__ part) {
  __shared__ __align__(16) float xs[8 * 64 * 20];  // 40 KB, [ii][b][20]
  const int tid = threadIdx.x;
  const int b = tid & 63;
  const int og = __builtin_amdgcn_readfirstlane(tid >> 6);  // 0..3, wave-uniform
  const int o0 = blockIdx.x * 8 + og * 2;
  const int ic = blockIdx.y;
  float rfv[16];
#pragma unroll
  for (int e = 0; e < 16; ++e) rfv[e] = rf[b * 16 + e];
  float acc0[16], acc1[16];
#pragma unroll
  for (int t = 0; t < 16; ++t) { acc0[t] = 0.f; acc1[t] = 0.f; }
  const float* wb = weight + (size_t)o0 * 1536;  // + e*786432 + i*3
#pragma unroll 1
  for (int sub = 0; sub < 8; ++sub) {
    const int i0 = ic * 64 + sub * 8;
    __syncthreads();
    const float4* src = (const float4*)(xt + (size_t)i0 * 1280);
    float4* dst = (float4*)xs;
#pragma unroll
    for (int j = 0; j < 10; ++j) dst[tid + j * 256] = src[tid + j * 256];
    __syncthreads();
#pragma unroll
    for (int ii = 0; ii < 8; ++ii) {
      const int i = i0 + ii;
      const float* wp = wb + i * 3;
      // synthesis: w[o2][k] = sum_e rf[b,e] * weight[e,o0+o2,i,k]  (weight via s_load)
      float w00 = 0, w01 = 0, w02 = 0, w10 = 0, w11 = 0, w12 = 0;
#pragma unroll
      for (int e = 0; e < 16; ++e) {
        const float* we = wp + e * 786432;
        float r = rfv[e];
        w00 = fmaf(r, we[0], w00);
        w01 = fmaf(r, we[1], w01);
        w02 = fmaf(r, we[2], w02);
        w10 = fmaf(r, we[1536], w10);
        w11 = fmaf(r, we[1537], w11);
        w12 = fmaf(r, we[1538], w12);
      }
      // x row (18 valid floats, padded layout 20) via wide LDS reads
      const float* xr = &xs[(ii * 64 + b) * 20];
      float xv[18];
      *(float4*)&xv[0] = *(const float4*)&xr[0];
      *(float4*)&xv[4] = *(const float4*)&xr[4];
      *(float4*)&xv[8] = *(const float4*)&xr[8];
      *(float4*)&xv[12] = *(const float4*)&xr[12];
      *(float2*)&xv[16] = *(const float2*)&xr[16];
#pragma unroll
      for (int t = 0; t < 16; ++t) {
        float a0 = acc0[t], a1 = acc1[t];
        a0 = fmaf(w00, xv[t], a0);
        a0 = fmaf(w01, xv[t + 1], a0);
        a0 = fmaf(w02, xv[t + 2], a0);
        a1 = fmaf(w10, xv[t], a1);
        a1 = fmaf(w11, xv[t + 1], a1);
        a1 = fmaf(w12, xv[t + 2], a1);
        acc0[t] = a0;
        acc1[t] = a1;
      }
    }
  }
  // partials: part[ic][b][o][t], each thread writes 2 full 64B rows
  float4* p4 = (float4*)(part + (((size_t)ic * 64 + b) * 512 + o0) * 16);
#pragma unroll
  for (int t4 = 0; t4 < 4; ++t4)
    p4[t4] = make_float4(acc0[t4 * 4], acc0[t4 * 4 + 1], acc0[t4 * 4 + 2], acc0[t4 * 4 + 3]);
#pragma unroll
  for (int t4 = 0; t4 < 4; ++t4)
    p4[4 + t4] = make_float4(acc1[t4 * 4], acc1[t4 * 4 + 1], acc1[t4 * 4 + 2], acc1[t4 * 4 + 3]);
}

// K3: out = sum_ic part + rf@bias + 1
__global__ __launch_bounds__(256) void k3_reduce(const float* __restrict__ part,
                                                 const float* __restrict__ rf,
                                                 const float* __restrict__ bias,
                                                 float* __restrict__ out) {
  int g = blockIdx.x * 256 + threadIdx.x;  // f4 index 0..131071
  int b = g >> 11;
  int o = (g >> 2) & 511;
  float4 s = make_float4(1.f, 1.f, 1.f, 1.f);
#pragma unroll
  for (int ic = 0; ic < 8; ++ic) {
    float4 p = ((const float4*)part)[ic * 131072 + g];
    s.x += p.x;
    s.y += p.y;
    s.z += p.z;
    s.w += p.w;
  }
  int bu = __builtin_amdgcn_readfirstlane(b);  // wave-uniform -> s_load for rf
  float bb = 0.f;
#pragma unroll
  for (int e = 0; e < 16; ++e) bb = fmaf(rf[bu * 16 + e], bias[e * 512 + o], bb);
  s.x += bb;
  s.y += bb;
  s.z += bb;
  s.w += bb;
  ((float4*)out)[g] = s;
}

extern "C" void kernel_launch(void* const* d_in, const int* in_sizes, int n_in,
                              void* d_out, int out_size, void* d_ws, size_t ws_size,
                              hipStream_t stream) {
  const float* x = (const float*)d_in[0];
  const float* rf_w = (const float*)d_in[1];
  const float* rf_b = (const float*)d_in[2];
  const float* weight = (const float*)d_in[3];
  const float* bias = (const float*)d_in[4];
  float* out = (float*)d_out;
  float* ws = (float*)d_ws;

  float* rf = ws;                // 1024
  float* pooled = ws + 1024;     // 32768
  float* xt = ws + 33792;        // 655360
  float* part = ws + 689152;     // 4194304

  k1_transpose_pool<<<128, 256, 0, stream>>>(x, pooled, xt);
  k1b_rf<<<4, 256, 0, stream>>>(pooled, rf_w, rf_b, rf);
  k2_main<<<dim3(64, 8), 256, 0, stream>>>(weight, xt, rf, part);
  k3_reduce<<<512, 256, 0, stream>>>(part, rf, bias, out);
}